// Round 18
// baseline (146.972 us; speedup 1.0000x reference)
//
#include <hip/hip_runtime.h>
#include <hip/hip_fp16.h>

#define NN 50000
#define NE 800000

typedef unsigned short u16;
typedef float v2f __attribute__((ext_vector_type(2)));
typedef short bf16x8 __attribute__((ext_vector_type(8)));
typedef float f32x4 __attribute__((ext_vector_type(4)));

// ---- DPP reduces on the VALU pipe ----
template <int CTRL>
__device__ __forceinline__ float dpp_add(float p) {
  const int v = __builtin_amdgcn_update_dpp(0, __float_as_int(p), CTRL, 0xF, 0xF, true);
  return p + __int_as_float(v);
}
__device__ __forceinline__ float red16(float p) {
  p = dpp_add<0xB1>(p);   // xor1
  p = dpp_add<0x4E>(p);   // xor2
  p = dpp_add<0x141>(p);  // row_half_mirror (xor4-equivalent within 8)
  p = dpp_add<0x140>(p);  // row_mirror (cross-8 within 16)
  return p;
}
__device__ __forceinline__ float red8(float p) {   // all-reduce within 8-lane groups
  p = dpp_add<0xB1>(p);
  p = dpp_add<0x4E>(p);
  p = dpp_add<0x141>(p);
  return p;
}

__device__ __forceinline__ unsigned short f2bf(float f) {  // RNE fp32->bf16
  unsigned u = __float_as_uint(f);
  return (unsigned short)((u + 0x7FFFu + ((u >> 16) & 1u)) >> 16);
}
__device__ __forceinline__ unsigned pk2(float a, float b) {
  return (unsigned)f2bf(a) | ((unsigned)f2bf(b) << 16);
}

// ---------------- K1: MFMA QKV + skip GEMM (64-node tile) + histogram -------
__global__ __launch_bounds__(256) void k_gemm_qkv(
    const float* __restrict__ x,
    const float* __restrict__ Wq, const float* __restrict__ bq,
    const float* __restrict__ Wk, const float* __restrict__ bk,
    const float* __restrict__ Wv, const float* __restrict__ bv,
    const float* __restrict__ Wskip, const float* __restrict__ bskip,
    const int* __restrict__ ei, int* __restrict__ cnt, int* __restrict__ pos,
    float* __restrict__ qs, unsigned* __restrict__ kvp, float* __restrict__ skip)
{
  const int t = threadIdx.x;

  if (blockIdx.y == 1) {  // histogram slice (+ per-edge bucket position)
    const int e0 = blockIdx.x * 1024 + t;
    #pragma unroll
    for (int it = 0; it < 4; it++) {
      const int e = e0 + it * 256;
      if (e < NE) pos[e] = atomicAdd(&cnt[ei[NE + e]], 1);
    }
    return;
  }

  __shared__ unsigned short xb[64][72];  // bf16 x tile, padded
  __shared__ unsigned short wb[64][72];  // bf16 W slice, padded
  __shared__ float cb[64][68];           // fp32 bounce for k/v repack
  const int tileN = blockIdx.x * 64;

  {  // stage x -> bf16 LDS
    const int nl = t >> 2, c0 = (t & 3) * 16;
    const int n = tileN + nl;
    float4 a0, a1, a2, a3;
    if (n < NN) {
      const float4* xr = (const float4*)(x + (size_t)n * 64 + c0);
      a0 = xr[0]; a1 = xr[1]; a2 = xr[2]; a3 = xr[3];
    } else {
      a0 = a1 = a2 = a3 = make_float4(0.f, 0.f, 0.f, 0.f);
    }
    *(uint4*)&xb[nl][c0] =
        make_uint4(pk2(a0.x, a0.y), pk2(a0.z, a0.w), pk2(a1.x, a1.y), pk2(a1.z, a1.w));
    *(uint4*)&xb[nl][c0 + 8] =
        make_uint4(pk2(a2.x, a2.y), pk2(a2.z, a2.w), pk2(a3.x, a3.y), pk2(a3.z, a3.w));
  }

  const int w = t >> 6;          // wave -> 16-node row tile
  const int l = t & 63;
  const int rb = w * 16;
  const int frow = l & 15;
  const int fk = (l >> 4) * 8;

  const bf16x8 a0 = *(const bf16x8*)&xb[rb + frow][fk];
  const bf16x8 a1 = *(const bf16x8*)&xb[rb + frow][fk + 32];

  for (int s = 0; s < 7; s++) {
    const float* Wb; const float* bias; int cbase; int kind;  // 0 q,1 skip,2 k,3 v
    switch (s) {
      case 0: Wb = Wq;    bias = bq;    cbase = 0;  kind = 0; break;
      case 1: Wb = Wq;    bias = bq;    cbase = 64; kind = 0; break;
      case 2: Wb = Wk;    bias = bk;    cbase = 0;  kind = 2; break;
      case 3: Wb = Wv;    bias = bv;    cbase = 0;  kind = 3; break;
      case 4: Wb = Wk;    bias = bk;    cbase = 64; kind = 2; break;
      case 5: Wb = Wv;    bias = bv;    cbase = 64; kind = 3; break;
      default: Wb = Wskip; bias = bskip; cbase = 0; kind = 1; break;
    }

    __syncthreads();
    {
      const int nl = t >> 2, c0 = (t & 3) * 16;
      const float4* wr = (const float4*)(Wb + (size_t)(cbase + nl) * 64 + c0);
      float4 b0 = wr[0], b1 = wr[1], b2 = wr[2], b3 = wr[3];
      *(uint4*)&wb[nl][c0] =
          make_uint4(pk2(b0.x, b0.y), pk2(b0.z, b0.w), pk2(b1.x, b1.y), pk2(b1.z, b1.w));
      *(uint4*)&wb[nl][c0 + 8] =
          make_uint4(pk2(b2.x, b2.y), pk2(b2.z, b2.w), pk2(b3.x, b3.y), pk2(b3.z, b3.w));
    }
    __syncthreads();

    #pragma unroll
    for (int ct = 0; ct < 4; ct++) {
      const bf16x8 b0 = *(const bf16x8*)&wb[ct * 16 + frow][fk];
      const bf16x8 b1 = *(const bf16x8*)&wb[ct * 16 + frow][fk + 32];
      f32x4 acc = {0.f, 0.f, 0.f, 0.f};
      acc = __builtin_amdgcn_mfma_f32_16x16x32_bf16(a0, b0, acc, 0, 0, 0);
      acc = __builtin_amdgcn_mfma_f32_16x16x32_bf16(a1, b1, acc, 0, 0, 0);
      const int col = ct * 16 + frow;
      const int row0 = rb + ((l >> 4) << 2);
      const float bb = bias[cbase * (kind != 1 ? 1 : 0) + col];
      if (kind == 0) {
        #pragma unroll
        for (int j = 0; j < 4; j++) {
          const int n = tileN + row0 + j;
          if (n < NN) qs[(size_t)n * 128 + cbase + col] = acc[j] + bb;
        }
      } else if (kind == 1) {
        #pragma unroll
        for (int j = 0; j < 4; j++) {
          const int n = tileN + row0 + j;
          if (n < NN) skip[(size_t)n * 64 + col] = acc[j] + bb;
        }
      } else {
        #pragma unroll
        for (int j = 0; j < 4; j++) cb[row0 + j][col] = acc[j] + bb;
      }
    }

    if (kind >= 2) {  // fp8 repack from this wave's own cb rows (intra-wave)
      const int rrow = rb + (l >> 2);
      const int chb = (l & 3) * 16;
      const int n = tileN + rrow;
      if (n < NN) {
        const float4* c4 = (const float4*)&cb[rrow][chb];
        const float4 c0_ = c4[0], c1_ = c4[1], c2_ = c4[2], c3_ = c4[3];
        unsigned p0 = 0, p1 = 0, p2 = 0, p3 = 0;
        p0 = __builtin_amdgcn_cvt_pk_fp8_f32(c0_.x, c0_.y, p0, false);
        p0 = __builtin_amdgcn_cvt_pk_fp8_f32(c0_.z, c0_.w, p0, true);
        p1 = __builtin_amdgcn_cvt_pk_fp8_f32(c1_.x, c1_.y, p1, false);
        p1 = __builtin_amdgcn_cvt_pk_fp8_f32(c1_.z, c1_.w, p1, true);
        p2 = __builtin_amdgcn_cvt_pk_fp8_f32(c2_.x, c2_.y, p2, false);
        p2 = __builtin_amdgcn_cvt_pk_fp8_f32(c2_.z, c2_.w, p2, true);
        p3 = __builtin_amdgcn_cvt_pk_fp8_f32(c3_.x, c3_.y, p3, false);
        p3 = __builtin_amdgcn_cvt_pk_fp8_f32(c3_.z, c3_.w, p3, true);
        const int ebase = (cbase + chb) >> 2;
        unsigned* dstp = kvp + (size_t)n * 64 + ebase * 2 + ((kind == 3) ? 1 : 0);
        dstp[0] = p0; dstp[2] = p1; dstp[4] = p2; dstp[6] = p3;
      }
    }
  }
}

// ---------------- S2: single merged scan (49 blocks; self-computed prefix) --
__global__ __launch_bounds__(1024) void k_scan(
    const int* __restrict__ cnt, int* __restrict__ rowptr) {
  __shared__ int wsum[16];
  __shared__ int boff_s;
  const int t = threadIdx.x, lane = t & 63, wid = t >> 6;
  const int b = blockIdx.x;

  {  // prefix: sum of cnt[0 .. b*1024)
    int pre = 0;
    for (int j = t; j < b * 1024; j += 1024) pre += cnt[j];
    #pragma unroll
    for (int m = 1; m <= 32; m <<= 1) pre += __shfl_xor(pre, m);
    if (lane == 0) wsum[wid] = pre;
    __syncthreads();
    if (t == 0) {
      int s = 0;
      #pragma unroll
      for (int j = 0; j < 16; j++) s += wsum[j];
      boff_s = s;
    }
    __syncthreads();
  }

  const int i = b * 1024 + t;
  const int val = (i < NN) ? cnt[i] : 0;
  int incl = val;
  #pragma unroll
  for (int off = 1; off < 64; off <<= 1) {
    int n = __shfl_up(incl, off, 64);
    if (lane >= off) incl += n;
  }
  if (lane == 63) wsum[wid] = incl;
  __syncthreads();
  if (t < 16) {
    int wv = wsum[t];
    int wincl = wv;
    #pragma unroll
    for (int off = 1; off < 16; off <<= 1) {
      int n = __shfl_up(wincl, off, 64);
      if (t >= off) wincl += n;
    }
    wsum[t] = wincl - wv;
  }
  __syncthreads();
  if (i < NN) rowptr[i] = boff_s + wsum[wid] + incl - val;
  if (b == 0 && t == 0) rowptr[NN] = NE;
}

// ---------------- S3: pure scatter fill (no atomics), 4B records ------------
__global__ __launch_bounds__(256) void k_fill(
    const int* __restrict__ ei, const float* __restrict__ ea,
    const int* __restrict__ rowptr, const int* __restrict__ pos,
    unsigned* __restrict__ epk) {
  const int e = blockIdx.x * 256 + threadIdx.x;
  if (e < NE) {
    const int dst = ei[NE + e];
    const int idx = rowptr[dst] + pos[e];
    const unsigned rec = (unsigned)ei[e] |
        ((unsigned)__half_as_ushort(__float2half_rn(ea[e])) << 16);
    epk[idx] = rec;
  }
}

// ------- K2: per-dst softmax + agg; QUARTER-wave (16 lanes x 8ch) per edge --
__global__ __launch_bounds__(256) void k_fused(
    const float* __restrict__ qs, const unsigned* __restrict__ kvp,
    const float* __restrict__ skip, const float* __restrict__ x,
    const int* __restrict__ rowptr, const unsigned* __restrict__ epk,
    const float* __restrict__ We,
    const float* __restrict__ Wl, const float* __restrict__ bl,
    const float* __restrict__ g0, const float* __restrict__ b0,
    const float* __restrict__ g1, const float* __restrict__ b1,
    float* __restrict__ out)
{
  __shared__ float wlT[64][65];   // wlT[k][j] = Wl[j][k]
  __shared__ float scx[4][64];    // per-wave scratch (transpose + x1 broadcast)
  const int t = threadIdx.x;
  {
    const int jl = t >> 2, c0 = (t & 3) * 16;
    const float4* wr = (const float4*)(Wl + (size_t)jl * 64 + c0);
    float4 w0 = wr[0], w1 = wr[1], w2 = wr[2], w3 = wr[3];
    wlT[c0 +  0][jl] = w0.x; wlT[c0 +  1][jl] = w0.y; wlT[c0 +  2][jl] = w0.z; wlT[c0 +  3][jl] = w0.w;
    wlT[c0 +  4][jl] = w1.x; wlT[c0 +  5][jl] = w1.y; wlT[c0 +  6][jl] = w1.z; wlT[c0 +  7][jl] = w1.w;
    wlT[c0 +  8][jl] = w2.x; wlT[c0 +  9][jl] = w2.y; wlT[c0 + 10][jl] = w2.z; wlT[c0 + 11][jl] = w2.w;
    wlT[c0 + 12][jl] = w3.x; wlT[c0 + 13][jl] = w3.y; wlT[c0 + 14][jl] = w3.z; wlT[c0 + 15][jl] = w3.w;
  }
  __syncthreads();  // the ONLY barrier

  const int w = t >> 6;
  const int dst = __builtin_amdgcn_readfirstlane(blockIdx.x * 4 + w);
  const int lane = t & 63;
  const int q4 = lane >> 4;      // quarter index: which edge of 4
  const int ql = lane & 15;      // lane-in-quarter: 8-channel group (ch 8*ql..8*ql+7)

  // q and We: 8 channels per lane
  const float4 qv0 = ((const float4*)(qs + (size_t)dst * 128))[ql * 2];
  const float4 qv1 = ((const float4*)(qs + (size_t)dst * 128))[ql * 2 + 1];
  const float4 we0 = ((const float4*)We)[ql * 2];
  const float4 we1 = ((const float4*)We)[ql * 2 + 1];
  const float skipv = skip[(size_t)dst * 64 + lane];
  const float xv    = x[(size_t)dst * 64 + lane];

  // per-head qwe: ql<8 lanes hold head0 channels, ql>=8 head1 -> red8
  const float qwe = red8(qv0.x * we0.x + qv0.y * we0.y + qv0.z * we0.z + qv0.w * we0.w +
                         qv1.x * we1.x + qv1.y * we1.y + qv1.z * we1.z + qv1.w * we1.w);

  const int base = rowptr[dst];
  const int deg  = rowptr[dst + 1] - base;
  const uint4* kv16 = (const uint4*)kvp;   // 16B = entries {k(e),v(e),k(e+1),v(e+1)}
  const unsigned* ep = epk + base;

  float s = 0.f, sw = 0.f;
  float sv0 = 0.f, sv1 = 0.f, sv2 = 0.f, sv3 = 0.f;
  float sv4 = 0.f, sv5 = 0.f, sv6 = 0.f, sv7 = 0.f;

  const float SCL = 0.18033688011112042f;  // 0.125*log2(e)

#define UNPACK_W(er) __half2float(__ushort_as_half((unsigned short)((er) >> 16)))
#define PROC4(u, wg, mask)                                                  \
  {                                                                         \
    const v2f k01 = __builtin_amdgcn_cvt_pk_f32_fp8((u).x, false);          \
    const v2f k23 = __builtin_amdgcn_cvt_pk_f32_fp8((u).x, true);           \
    const v2f v01 = __builtin_amdgcn_cvt_pk_f32_fp8((u).y, false);          \
    const v2f v23 = __builtin_amdgcn_cvt_pk_f32_fp8((u).y, true);           \
    const v2f k45 = __builtin_amdgcn_cvt_pk_f32_fp8((u).z, false);          \
    const v2f k67 = __builtin_amdgcn_cvt_pk_f32_fp8((u).z, true);           \
    const v2f v45 = __builtin_amdgcn_cvt_pk_f32_fp8((u).w, false);          \
    const v2f v67 = __builtin_amdgcn_cvt_pk_f32_fp8((u).w, true);           \
    float p = qv0.x * k01.x + qv0.y * k01.y + qv0.z * k23.x + qv0.w * k23.y \
            + qv1.x * k45.x + qv1.y * k45.y + qv1.z * k67.x + qv1.w * k67.y;\
    p = red8(p);                                                            \
    float e_ = exp2f((p + (wg) * qwe) * SCL);                               \
    e_ = (mask) ? e_ : 0.f;                                                 \
    s += e_; sw += e_ * (wg);                                               \
    sv0 += e_ * v01.x; sv1 += e_ * v01.y;                                   \
    sv2 += e_ * v23.x; sv3 += e_ * v23.y;                                   \
    sv4 += e_ * v45.x; sv5 += e_ * v45.y;                                   \
    sv6 += e_ * v67.x; sv7 += e_ * v67.y;                                   \
  }

  int i = 0;
  for (; i + 8 <= deg; i += 8) {
    const unsigned er0 = ep[i + q4];
    const unsigned er1 = ep[i + 4 + q4];
    const uint4 u0 = kv16[(size_t)(er0 & 0xFFFFu) * 16 + ql];
    const uint4 u1 = kv16[(size_t)(er1 & 0xFFFFu) * 16 + ql];
    PROC4(u0, UNPACK_W(er0), true)
    PROC4(u1, UNPACK_W(er1), true)
  }
  for (; i < deg; i += 4) {
    const int idx = i + q4;
    const bool valid = idx < deg;
    const unsigned er = ep[valid ? idx : (deg - 1)];
    const uint4 u = kv16[(size_t)(er & 0xFFFFu) * 16 + ql];
    PROC4(u, UNPACK_W(er), valid)
  }
#undef PROC4
#undef UNPACK_W

  // combine the four quarter-wave partial accumulators (xor16 + xor32)
  #pragma unroll
  for (int m = 16; m <= 32; m <<= 1) {
    s   += __shfl_xor(s, m);   sw  += __shfl_xor(sw, m);
    sv0 += __shfl_xor(sv0, m); sv1 += __shfl_xor(sv1, m);
    sv2 += __shfl_xor(sv2, m); sv3 += __shfl_xor(sv3, m);
    sv4 += __shfl_xor(sv4, m); sv5 += __shfl_xor(sv5, m);
    sv6 += __shfl_xor(sv6, m); sv7 += __shfl_xor(sv7, m);
  }

  float a0 = 0.f, a1 = 0.f, a2 = 0.f, a3 = 0.f;
  float a4 = 0.f, a5 = 0.f, a6 = 0.f, a7 = 0.f;
  if (deg > 0) {
    const float inv = 1.f / s;
    a0 = (sv0 + sw * we0.x) * inv; a1 = (sv1 + sw * we0.y) * inv;
    a2 = (sv2 + sw * we0.z) * inv; a3 = (sv3 + sw * we0.w) * inv;
    a4 = (sv4 + sw * we1.x) * inv; a5 = (sv5 + sw * we1.y) * inv;
    a6 = (sv6 + sw * we1.z) * inv; a7 = (sv7 + sw * we1.w) * inv;
  }
  // head mean: lane ql (head0, ql<8) pairs with lane ql+8 (head1)
  a0 = 0.5f * (a0 + __shfl_xor(a0, 8));
  a1 = 0.5f * (a1 + __shfl_xor(a1, 8));
  a2 = 0.5f * (a2 + __shfl_xor(a2, 8));
  a3 = 0.5f * (a3 + __shfl_xor(a3, 8));
  a4 = 0.5f * (a4 + __shfl_xor(a4, 8));
  a5 = 0.5f * (a5 + __shfl_xor(a5, 8));
  a6 = 0.5f * (a6 + __shfl_xor(a6, 8));
  a7 = 0.5f * (a7 + __shfl_xor(a7, 8));
  if (lane < 8) {
    ((float4*)scx[w])[lane * 2]     = make_float4(a0, a1, a2, a3);
    ((float4*)scx[w])[lane * 2 + 1] = make_float4(a4, a5, a6, a7);
  }
  const float hv = scx[w][lane] + skipv;   // intra-wave LDS, no barrier

  // LN0 via dual moments
  float m1 = hv, m2 = hv * hv;
  m1 = red16(m1); m2 = red16(m2);
  m1 += __shfl_xor(m1, 16); m2 += __shfl_xor(m2, 16);
  m1 += __shfl_xor(m1, 32); m2 += __shfl_xor(m2, 32);
  const float mean = m1 * (1.f / 64.f);
  const float var = fmaxf(m2 * (1.f / 64.f) - mean * mean, 0.f);
  const float x1 = xv + (hv - mean) * rsqrtf(var + 1e-5f) * g0[lane] + b0[lane];

  // y = x1 @ Wl^T + bl via per-wave LDS broadcast
  scx[w][lane] = x1;
  float y0 = 0.f, y1 = 0.f, y2 = 0.f, y3 = 0.f;
  #pragma unroll
  for (int kk = 0; kk < 64; kk += 4) {
    const float4 xb4 = *(const float4*)&scx[w][kk];
    y0 += xb4.x * wlT[kk][lane];
    y1 += xb4.y * wlT[kk + 1][lane];
    y2 += xb4.z * wlT[kk + 2][lane];
    y3 += xb4.w * wlT[kk + 3][lane];
  }
  const float y = bl[lane] + (y0 + y1) + (y2 + y3);

  // LN1 via dual moments
  float n1 = y, n2 = y * y;
  n1 = red16(n1); n2 = red16(n2);
  n1 += __shfl_xor(n1, 16); n2 += __shfl_xor(n2, 16);
  n1 += __shfl_xor(n1, 32); n2 += __shfl_xor(n2, 32);
  const float mean2 = n1 * (1.f / 64.f);
  const float var2 = fmaxf(n2 * (1.f / 64.f) - mean2 * mean2, 0.f);
  out[(size_t)dst * 64 + lane] = x1 + (y - mean2) * rsqrtf(var2 + 1e-5f) * g1[lane] + b1[lane];
}

extern "C" void kernel_launch(void* const* d_in, const int* in_sizes, int n_in,
                              void* d_out, int out_size, void* d_ws, size_t ws_size,
                              hipStream_t stream) {
  const float* x     = (const float*)d_in[0];
  const int*   ei    = (const int*)d_in[1];
  const float* ea    = (const float*)d_in[2];
  const float* Wq    = (const float*)d_in[3];
  const float* bq    = (const float*)d_in[4];
  const float* Wk    = (const float*)d_in[5];
  const float* bk    = (const float*)d_in[6];
  const float* Wv    = (const float*)d_in[7];
  const float* bv    = (const float*)d_in[8];
  const float* We    = (const float*)d_in[9];
  const float* Wskip = (const float*)d_in[10];
  const float* bskip = (const float*)d_in[11];
  const float* Wl    = (const float*)d_in[12];
  const float* bl    = (const float*)d_in[13];
  const float* g0    = (const float*)d_in[14];
  const float* b0    = (const float*)d_in[15];
  const float* g1    = (const float*)d_in[16];
  const float* b1    = (const float*)d_in[17];
  float* out = (float*)d_out;

  float* ws = (float*)d_ws;
  size_t off = 0;
  float* qs   = ws + off; off += (size_t)NN * 128;
  unsigned* kvp = (unsigned*)(ws + off); off += (size_t)NN * 64;  // 256B/node fp8
  float* skip = ws + off; off += (size_t)NN * 64;
  int* cnt    = (int*)(ws + off); off += NN;
  int* rowptr = (int*)(ws + off); off += NN + 1;
  int* pos    = (int*)(ws + off); off += NE;
  unsigned* epk = (unsigned*)(ws + off); off += NE;

  (void)hipMemsetAsync(cnt, 0, (size_t)NN * sizeof(int), stream);

  dim3 gGemm((NN + 63) / 64, 2);  // y==1 -> histogram+pos slice
  hipLaunchKernelGGL(k_gemm_qkv, gGemm, dim3(256), 0, stream,
                     x, Wq, bq, Wk, bk, Wv, bv, Wskip, bskip, ei, cnt, pos, qs, kvp, skip);
  hipLaunchKernelGGL(k_scan, dim3(49), dim3(1024), 0, stream, cnt, rowptr);
  hipLaunchKernelGGL(k_fill, dim3((NE + 255) / 256), dim3(256), 0, stream,
                     ei, ea, rowptr, pos, epk);
  hipLaunchKernelGGL(k_fused, dim3(NN / 4), dim3(256), 0, stream,
                     qs, kvp, skip, x, rowptr, epk, We,
                     Wl, bl, g0, b0, g1, b1, out);
}

// Round 19
// 146.174 us; speedup vs baseline: 1.0055x; 1.0055x over previous
//
#include <hip/hip_runtime.h>
#include <hip/hip_fp16.h>

#define NN 50000
#define NE 800000

typedef unsigned short u16;
typedef float v2f __attribute__((ext_vector_type(2)));
typedef short bf16x8 __attribute__((ext_vector_type(8)));
typedef float f32x4 __attribute__((ext_vector_type(4)));

// ---- DPP reduces on the VALU pipe ----
template <int CTRL>
__device__ __forceinline__ float dpp_add(float p) {
  const int v = __builtin_amdgcn_update_dpp(0, __float_as_int(p), CTRL, 0xF, 0xF, true);
  return p + __int_as_float(v);
}
__device__ __forceinline__ float red16(float p) {
  p = dpp_add<0xB1>(p);   // xor1
  p = dpp_add<0x4E>(p);   // xor2
  p = dpp_add<0x141>(p);  // row_half_mirror
  p = dpp_add<0x140>(p);  // row_mirror
  return p;
}

__device__ __forceinline__ unsigned short f2bf(float f) {  // RNE fp32->bf16
  unsigned u = __float_as_uint(f);
  return (unsigned short)((u + 0x7FFFu + ((u >> 16) & 1u)) >> 16);
}
__device__ __forceinline__ unsigned pk2(float a, float b) {
  return (unsigned)f2bf(a) | ((unsigned)f2bf(b) << 16);
}

// ---------------- H: histogram + per-edge bucket position -------------------
__global__ __launch_bounds__(256) void k_hist(
    const int* __restrict__ ei, int* __restrict__ cnt, int* __restrict__ pos) {
  const int e0 = blockIdx.x * 1024 + threadIdx.x;
  #pragma unroll
  for (int it = 0; it < 4; it++) {
    const int e = e0 + it * 256;
    if (e < NE) pos[e] = atomicAdd(&cnt[ei[NE + e]], 1);
  }
}

// ---------------- S2: single merged scan (49 blocks; self-computed prefix) --
__global__ __launch_bounds__(1024) void k_scan(
    const int* __restrict__ cnt, int* __restrict__ rowptr) {
  __shared__ int wsum[16];
  __shared__ int boff_s;
  const int t = threadIdx.x, lane = t & 63, wid = t >> 6;
  const int b = blockIdx.x;

  {  // prefix: sum of cnt[0 .. b*1024)
    int pre = 0;
    for (int j = t; j < b * 1024; j += 1024) pre += cnt[j];
    #pragma unroll
    for (int m = 1; m <= 32; m <<= 1) pre += __shfl_xor(pre, m);
    if (lane == 0) wsum[wid] = pre;
    __syncthreads();
    if (t == 0) {
      int s = 0;
      #pragma unroll
      for (int j = 0; j < 16; j++) s += wsum[j];
      boff_s = s;
    }
    __syncthreads();
  }

  const int i = b * 1024 + t;
  const int val = (i < NN) ? cnt[i] : 0;
  int incl = val;
  #pragma unroll
  for (int off = 1; off < 64; off <<= 1) {
    int n = __shfl_up(incl, off, 64);
    if (lane >= off) incl += n;
  }
  if (lane == 63) wsum[wid] = incl;
  __syncthreads();
  if (t < 16) {
    int wv = wsum[t];
    int wincl = wv;
    #pragma unroll
    for (int off = 1; off < 16; off <<= 1) {
      int n = __shfl_up(wincl, off, 64);
      if (t >= off) wincl += n;
    }
    wsum[t] = wincl - wv;
  }
  __syncthreads();
  if (i < NN) rowptr[i] = boff_s + wsum[wid] + incl - val;
  if (b == 0 && t == 0) rowptr[NN] = NE;
}

// ---------------- K1: MFMA QKV/skip GEMM (y==0) + edge FILL (y==1) ----------
// Fill runs concurrently with the GEMM compute inside one dispatch.
__global__ __launch_bounds__(256) void k_gemm_qkv(
    const float* __restrict__ x,
    const float* __restrict__ Wq, const float* __restrict__ bq,
    const float* __restrict__ Wk, const float* __restrict__ bk,
    const float* __restrict__ Wv, const float* __restrict__ bv,
    const float* __restrict__ Wskip, const float* __restrict__ bskip,
    const int* __restrict__ ei, const float* __restrict__ ea,
    const int* __restrict__ rowptr, const int* __restrict__ pos,
    unsigned* __restrict__ epk,
    float* __restrict__ qs, unsigned* __restrict__ kvp, float* __restrict__ skip)
{
  const int t = threadIdx.x;

  if (blockIdx.y == 1) {  // FILL slice: pure scatter (no atomics)
    const int e0 = blockIdx.x * 1024 + t;
    #pragma unroll
    for (int it = 0; it < 4; it++) {
      const int e = e0 + it * 256;
      if (e < NE) {
        const int dst = ei[NE + e];
        const int idx = rowptr[dst] + pos[e];
        epk[idx] = (unsigned)ei[e] |
            ((unsigned)__half_as_ushort(__float2half_rn(ea[e])) << 16);
      }
    }
    return;
  }

  __shared__ unsigned short xb[64][72];  // bf16 x tile, padded
  __shared__ unsigned short wb[64][72];  // bf16 W slice, padded
  __shared__ float cb[64][68];           // fp32 bounce for k/v repack
  const int tileN = blockIdx.x * 64;

  {  // stage x -> bf16 LDS
    const int nl = t >> 2, c0 = (t & 3) * 16;
    const int n = tileN + nl;
    float4 a0, a1, a2, a3;
    if (n < NN) {
      const float4* xr = (const float4*)(x + (size_t)n * 64 + c0);
      a0 = xr[0]; a1 = xr[1]; a2 = xr[2]; a3 = xr[3];
    } else {
      a0 = a1 = a2 = a3 = make_float4(0.f, 0.f, 0.f, 0.f);
    }
    *(uint4*)&xb[nl][c0] =
        make_uint4(pk2(a0.x, a0.y), pk2(a0.z, a0.w), pk2(a1.x, a1.y), pk2(a1.z, a1.w));
    *(uint4*)&xb[nl][c0 + 8] =
        make_uint4(pk2(a2.x, a2.y), pk2(a2.z, a2.w), pk2(a3.x, a3.y), pk2(a3.z, a3.w));
  }

  const int w = t >> 6;          // wave -> 16-node row tile
  const int l = t & 63;
  const int rb = w * 16;
  const int frow = l & 15;
  const int fk = (l >> 4) * 8;

  const bf16x8 a0 = *(const bf16x8*)&xb[rb + frow][fk];
  const bf16x8 a1 = *(const bf16x8*)&xb[rb + frow][fk + 32];

  for (int s = 0; s < 7; s++) {
    const float* Wb; const float* bias; int cbase; int kind;  // 0 q,1 skip,2 k,3 v
    switch (s) {
      case 0: Wb = Wq;    bias = bq;    cbase = 0;  kind = 0; break;
      case 1: Wb = Wq;    bias = bq;    cbase = 64; kind = 0; break;
      case 2: Wb = Wk;    bias = bk;    cbase = 0;  kind = 2; break;
      case 3: Wb = Wv;    bias = bv;    cbase = 0;  kind = 3; break;
      case 4: Wb = Wk;    bias = bk;    cbase = 64; kind = 2; break;
      case 5: Wb = Wv;    bias = bv;    cbase = 64; kind = 3; break;
      default: Wb = Wskip; bias = bskip; cbase = 0; kind = 1; break;
    }

    __syncthreads();
    {
      const int nl = t >> 2, c0 = (t & 3) * 16;
      const float4* wr = (const float4*)(Wb + (size_t)(cbase + nl) * 64 + c0);
      float4 b0 = wr[0], b1 = wr[1], b2 = wr[2], b3 = wr[3];
      *(uint4*)&wb[nl][c0] =
          make_uint4(pk2(b0.x, b0.y), pk2(b0.z, b0.w), pk2(b1.x, b1.y), pk2(b1.z, b1.w));
      *(uint4*)&wb[nl][c0 + 8] =
          make_uint4(pk2(b2.x, b2.y), pk2(b2.z, b2.w), pk2(b3.x, b3.y), pk2(b3.z, b3.w));
    }
    __syncthreads();

    #pragma unroll
    for (int ct = 0; ct < 4; ct++) {
      const bf16x8 b0 = *(const bf16x8*)&wb[ct * 16 + frow][fk];
      const bf16x8 b1 = *(const bf16x8*)&wb[ct * 16 + frow][fk + 32];
      f32x4 acc = {0.f, 0.f, 0.f, 0.f};
      acc = __builtin_amdgcn_mfma_f32_16x16x32_bf16(a0, b0, acc, 0, 0, 0);
      acc = __builtin_amdgcn_mfma_f32_16x16x32_bf16(a1, b1, acc, 0, 0, 0);
      const int col = ct * 16 + frow;
      const int row0 = rb + ((l >> 4) << 2);
      const float bb = bias[cbase * (kind != 1 ? 1 : 0) + col];
      if (kind == 0) {
        #pragma unroll
        for (int j = 0; j < 4; j++) {
          const int n = tileN + row0 + j;
          if (n < NN) qs[(size_t)n * 128 + cbase + col] = acc[j] + bb;
        }
      } else if (kind == 1) {
        #pragma unroll
        for (int j = 0; j < 4; j++) {
          const int n = tileN + row0 + j;
          if (n < NN) skip[(size_t)n * 64 + col] = acc[j] + bb;
        }
      } else {
        #pragma unroll
        for (int j = 0; j < 4; j++) cb[row0 + j][col] = acc[j] + bb;
      }
    }

    if (kind >= 2) {  // fp8 repack from this wave's own cb rows (intra-wave)
      const int rrow = rb + (l >> 2);
      const int chb = (l & 3) * 16;
      const int n = tileN + rrow;
      if (n < NN) {
        const float4* c4 = (const float4*)&cb[rrow][chb];
        const float4 c0_ = c4[0], c1_ = c4[1], c2_ = c4[2], c3_ = c4[3];
        unsigned p0 = 0, p1 = 0, p2 = 0, p3 = 0;
        p0 = __builtin_amdgcn_cvt_pk_fp8_f32(c0_.x, c0_.y, p0, false);
        p0 = __builtin_amdgcn_cvt_pk_fp8_f32(c0_.z, c0_.w, p0, true);
        p1 = __builtin_amdgcn_cvt_pk_fp8_f32(c1_.x, c1_.y, p1, false);
        p1 = __builtin_amdgcn_cvt_pk_fp8_f32(c1_.z, c1_.w, p1, true);
        p2 = __builtin_amdgcn_cvt_pk_fp8_f32(c2_.x, c2_.y, p2, false);
        p2 = __builtin_amdgcn_cvt_pk_fp8_f32(c2_.z, c2_.w, p2, true);
        p3 = __builtin_amdgcn_cvt_pk_fp8_f32(c3_.x, c3_.y, p3, false);
        p3 = __builtin_amdgcn_cvt_pk_fp8_f32(c3_.z, c3_.w, p3, true);
        const int ebase = (cbase + chb) >> 2;
        unsigned* dstp = kvp + (size_t)n * 64 + ebase * 2 + ((kind == 3) ? 1 : 0);
        dstp[0] = p0; dstp[2] = p1; dstp[4] = p2; dstp[6] = p3;
      }
    }
  }
}

// ------- K2: per-dst softmax + agg (fp8 kv, DPP reduce, 8-edge unroll),
//         single barrier after wlT staging; waves independent afterwards -----
__global__ __launch_bounds__(256) void k_fused(
    const float* __restrict__ qs, const unsigned* __restrict__ kvp,
    const float* __restrict__ skip, const float* __restrict__ x,
    const int* __restrict__ rowptr, const unsigned* __restrict__ epk,
    const float* __restrict__ We,
    const float* __restrict__ Wl, const float* __restrict__ bl,
    const float* __restrict__ g0, const float* __restrict__ b0,
    const float* __restrict__ g1, const float* __restrict__ b1,
    float* __restrict__ out)
{
  __shared__ float wlT[64][65];   // wlT[k][j] = Wl[j][k]
  __shared__ float scx[4][64];    // per-wave scratch (transpose + x1 broadcast)
  const int t = threadIdx.x;
  {
    const int jl = t >> 2, c0 = (t & 3) * 16;
    const float4* wr = (const float4*)(Wl + (size_t)jl * 64 + c0);
    float4 w0 = wr[0], w1 = wr[1], w2 = wr[2], w3 = wr[3];
    wlT[c0 +  0][jl] = w0.x; wlT[c0 +  1][jl] = w0.y; wlT[c0 +  2][jl] = w0.z; wlT[c0 +  3][jl] = w0.w;
    wlT[c0 +  4][jl] = w1.x; wlT[c0 +  5][jl] = w1.y; wlT[c0 +  6][jl] = w1.z; wlT[c0 +  7][jl] = w1.w;
    wlT[c0 +  8][jl] = w2.x; wlT[c0 +  9][jl] = w2.y; wlT[c0 + 10][jl] = w2.z; wlT[c0 + 11][jl] = w2.w;
    wlT[c0 + 12][jl] = w3.x; wlT[c0 + 13][jl] = w3.y; wlT[c0 + 14][jl] = w3.z; wlT[c0 + 15][jl] = w3.w;
  }
  __syncthreads();  // the ONLY barrier

  const int w = t >> 6;
  const int dst = __builtin_amdgcn_readfirstlane(blockIdx.x * 4 + w);
  const int lane = t & 63;
  const int half = lane >> 5;
  const int el = lane & 31;

  const float4 qv = ((const float4*)(qs + (size_t)dst * 128))[el];
  const float4 we4 = ((const float4*)We)[el];
  const float skipv = skip[(size_t)dst * 64 + lane];
  const float xv    = x[(size_t)dst * 64 + lane];

  const float qwe = red16(qv.x * we4.x + qv.y * we4.y + qv.z * we4.z + qv.w * we4.w);

  const int base = rowptr[dst];
  const int deg  = rowptr[dst + 1] - base;
  const uint2* kv8 = (const uint2*)kvp;
  const unsigned* ep = epk + base;

  float s = 0.f, sw = 0.f;
  float sv0 = 0.f, sv1 = 0.f, sv2 = 0.f, sv3 = 0.f;

  const float SCL = 0.18033688011112042f;  // 0.125*log2(e)

#define UNPACK_W(er) __half2float(__ushort_as_half((unsigned short)((er) >> 16)))
#define PROC(u, wg, mask)                                                   \
  {                                                                         \
    const v2f k01 = __builtin_amdgcn_cvt_pk_f32_fp8((u).x, false);          \
    const v2f k23 = __builtin_amdgcn_cvt_pk_f32_fp8((u).x, true);           \
    const v2f v01 = __builtin_amdgcn_cvt_pk_f32_fp8((u).y, false);          \
    const v2f v23 = __builtin_amdgcn_cvt_pk_f32_fp8((u).y, true);           \
    const float p = red16(qv.x * k01.x + qv.y * k01.y +                     \
                          qv.z * k23.x + qv.w * k23.y);                     \
    float e_ = exp2f((p + (wg) * qwe) * SCL);                               \
    e_ = (mask) ? e_ : 0.f;                                                 \
    s += e_; sw += e_ * (wg);                                               \
    sv0 += e_ * v01.x; sv1 += e_ * v01.y;                                   \
    sv2 += e_ * v23.x; sv3 += e_ * v23.y;                                   \
  }

  int i = 0;
  for (; i + 8 <= deg; i += 8) {
    const unsigned er0 = ep[i + half];
    const unsigned er1 = ep[i + 2 + half];
    const unsigned er2 = ep[i + 4 + half];
    const unsigned er3 = ep[i + 6 + half];
    const uint2 u0 = kv8[(size_t)(er0 & 0xFFFFu) * 32 + el];
    const uint2 u1 = kv8[(size_t)(er1 & 0xFFFFu) * 32 + el];
    const uint2 u2 = kv8[(size_t)(er2 & 0xFFFFu) * 32 + el];
    const uint2 u3 = kv8[(size_t)(er3 & 0xFFFFu) * 32 + el];
    PROC(u0, UNPACK_W(er0), true)
    PROC(u1, UNPACK_W(er1), true)
    PROC(u2, UNPACK_W(er2), true)
    PROC(u3, UNPACK_W(er3), true)
  }
  for (; i + 4 <= deg; i += 4) {
    const unsigned er0 = ep[i + half];
    const unsigned er1 = ep[i + 2 + half];
    const uint2 u0 = kv8[(size_t)(er0 & 0xFFFFu) * 32 + el];
    const uint2 u1 = kv8[(size_t)(er1 & 0xFFFFu) * 32 + el];
    PROC(u0, UNPACK_W(er0), true)
    PROC(u1, UNPACK_W(er1), true)
  }
  for (; i < deg; i += 2) {
    const int idx = i + half;
    const bool valid = idx < deg;
    const unsigned er = ep[valid ? idx : (deg - 1)];
    const uint2 u = kv8[(size_t)(er & 0xFFFFu) * 32 + el];
    PROC(u, UNPACK_W(er), valid)
  }
#undef PROC
#undef UNPACK_W

  s  += __shfl_xor(s, 32);
  sw += __shfl_xor(sw, 32);
  sv0 += __shfl_xor(sv0, 32); sv1 += __shfl_xor(sv1, 32);
  sv2 += __shfl_xor(sv2, 32); sv3 += __shfl_xor(sv3, 32);

  float a0 = 0.f, a1 = 0.f, a2 = 0.f, a3 = 0.f;
  if (deg > 0) {
    const float inv = 1.f / s;
    a0 = (sv0 + sw * we4.x) * inv;
    a1 = (sv1 + sw * we4.y) * inv;
    a2 = (sv2 + sw * we4.z) * inv;
    a3 = (sv3 + sw * we4.w) * inv;
  }
  a0 = 0.5f * (a0 + __shfl_xor(a0, 16));
  a1 = 0.5f * (a1 + __shfl_xor(a1, 16));
  a2 = 0.5f * (a2 + __shfl_xor(a2, 16));
  a3 = 0.5f * (a3 + __shfl_xor(a3, 16));
  if (half == 0 && el < 16) {
    ((float4*)scx[w])[el] = make_float4(a0, a1, a2, a3);
  }
  const float hv = scx[w][lane] + skipv;

  // LN0 via dual moments
  float m1 = hv, m2 = hv * hv;
  m1 = red16(m1); m2 = red16(m2);
  m1 += __shfl_xor(m1, 16); m2 += __shfl_xor(m2, 16);
  m1 += __shfl_xor(m1, 32); m2 += __shfl_xor(m2, 32);
  const float mean = m1 * (1.f / 64.f);
  const float var = fmaxf(m2 * (1.f / 64.f) - mean * mean, 0.f);
  const float x1 = xv + (hv - mean) * rsqrtf(var + 1e-5f) * g0[lane] + b0[lane];

  // y = x1 @ Wl^T + bl via per-wave LDS broadcast
  scx[w][lane] = x1;
  float y0 = 0.f, y1 = 0.f, y2 = 0.f, y3 = 0.f;
  #pragma unroll
  for (int kk = 0; kk < 64; kk += 4) {
    const float4 xb4 = *(const float4*)&scx[w][kk];
    y0 += xb4.x * wlT[kk][lane];
    y1 += xb4.y * wlT[kk + 1][lane];
    y2 += xb4.z * wlT[kk + 2][lane];
    y3 += xb4.w * wlT[kk + 3][lane];
  }
  const float y = bl[lane] + (y0 + y1) + (y2 + y3);

  // LN1 via dual moments
  float n1 = y, n2 = y * y;
  n1 = red16(n1); n2 = red16(n2);
  n1 += __shfl_xor(n1, 16); n2 += __shfl_xor(n2, 16);
  n1 += __shfl_xor(n1, 32); n2 += __shfl_xor(n2, 32);
  const float mean2 = n1 * (1.f / 64.f);
  const float var2 = fmaxf(n2 * (1.f / 64.f) - mean2 * mean2, 0.f);
  out[(size_t)dst * 64 + lane] = x1 + (y - mean2) * rsqrtf(var2 + 1e-5f) * g1[lane] + b1[lane];
}

extern "C" void kernel_launch(void* const* d_in, const int* in_sizes, int n_in,
                              void* d_out, int out_size, void* d_ws, size_t ws_size,
                              hipStream_t stream) {
  const float* x     = (const float*)d_in[0];
  const int*   ei    = (const int*)d_in[1];
  const float* ea    = (const float*)d_in[2];
  const float* Wq    = (const float*)d_in[3];
  const float* bq    = (const float*)d_in[4];
  const float* Wk    = (const float*)d_in[5];
  const float* bk    = (const float*)d_in[6];
  const float* Wv    = (const float*)d_in[7];
  const float* bv    = (const float*)d_in[8];
  const float* We    = (const float*)d_in[9];
  const float* Wskip = (const float*)d_in[10];
  const float* bskip = (const float*)d_in[11];
  const float* Wl    = (const float*)d_in[12];
  const float* bl    = (const float*)d_in[13];
  const float* g0    = (const float*)d_in[14];
  const float* b0    = (const float*)d_in[15];
  const float* g1    = (const float*)d_in[16];
  const float* b1    = (const float*)d_in[17];
  float* out = (float*)d_out;

  float* ws = (float*)d_ws;
  size_t off = 0;
  float* qs   = ws + off; off += (size_t)NN * 128;
  unsigned* kvp = (unsigned*)(ws + off); off += (size_t)NN * 64;  // 256B/node fp8
  float* skip = ws + off; off += (size_t)NN * 64;
  int* cnt    = (int*)(ws + off); off += NN;
  int* rowptr = (int*)(ws + off); off += NN + 1;
  int* pos    = (int*)(ws + off); off += NE;
  unsigned* epk = (unsigned*)(ws + off); off += NE;

  (void)hipMemsetAsync(cnt, 0, (size_t)NN * sizeof(int), stream);

  hipLaunchKernelGGL(k_hist, dim3((NE + 1023) / 1024), dim3(256), 0, stream, ei, cnt, pos);
  hipLaunchKernelGGL(k_scan, dim3(49), dim3(1024), 0, stream, cnt, rowptr);
  dim3 gGemm((NN + 63) / 64, 2);  // y=0: GEMM compute, y=1: edge fill (concurrent)
  hipLaunchKernelGGL(k_gemm_qkv, gGemm, dim3(256), 0, stream,
                     x, Wq, bq, Wk, bk, Wv, bv, Wskip, bskip,
                     ei, ea, rowptr, pos, epk, qs, kvp, skip);
  hipLaunchKernelGGL(k_fused, dim3(NN / 4), dim3(256), 0, stream,
                     qs, kvp, skip, x, rowptr, epk, We,
                     Wl, bl, g0, b0, g1, b1, out);
}

// Round 20
// 141.360 us; speedup vs baseline: 1.0397x; 1.0341x over previous
//
#include <hip/hip_runtime.h>
#include <hip/hip_fp16.h>

#define NN 50000
#define NE 800000

typedef unsigned short u16;
typedef float v2f __attribute__((ext_vector_type(2)));
typedef short bf16x8 __attribute__((ext_vector_type(8)));
typedef float f32x4 __attribute__((ext_vector_type(4)));

// ---- DPP reduces on the VALU pipe ----
template <int CTRL>
__device__ __forceinline__ float dpp_add(float p) {
  const int v = __builtin_amdgcn_update_dpp(0, __float_as_int(p), CTRL, 0xF, 0xF, true);
  return p + __int_as_float(v);
}
__device__ __forceinline__ float red16(float p) {
  p = dpp_add<0xB1>(p);   // xor1
  p = dpp_add<0x4E>(p);   // xor2
  p = dpp_add<0x141>(p);  // row_half_mirror
  p = dpp_add<0x140>(p);  // row_mirror
  return p;
}

__device__ __forceinline__ unsigned short f2bf(float f) {  // RNE fp32->bf16
  unsigned u = __float_as_uint(f);
  return (unsigned short)((u + 0x7FFFu + ((u >> 16) & 1u)) >> 16);
}
__device__ __forceinline__ unsigned pk2(float a, float b) {
  return (unsigned)f2bf(a) | ((unsigned)f2bf(b) << 16);
}

// ---------------- K1: MFMA QKV + skip GEMM (64-node tile) + histogram -------
// y==1: histogram+pos. y==0: GEMM via v_mfma_f32_16x16x32_bf16.
// q stored natural [n][128] fp32; kv [n][64] u32 fp8: entry e: k@2e, v@2e+1.
__global__ __launch_bounds__(256) void k_gemm_qkv(
    const float* __restrict__ x,
    const float* __restrict__ Wq, const float* __restrict__ bq,
    const float* __restrict__ Wk, const float* __restrict__ bk,
    const float* __restrict__ Wv, const float* __restrict__ bv,
    const float* __restrict__ Wskip, const float* __restrict__ bskip,
    const int* __restrict__ ei, int* __restrict__ cnt, int* __restrict__ pos,
    float* __restrict__ qs, unsigned* __restrict__ kvp, float* __restrict__ skip)
{
  const int t = threadIdx.x;

  if (blockIdx.y == 1) {  // histogram slice (+ per-edge bucket position)
    const int e0 = blockIdx.x * 1024 + t;
    #pragma unroll
    for (int it = 0; it < 4; it++) {
      const int e = e0 + it * 256;
      if (e < NE) pos[e] = atomicAdd(&cnt[ei[NE + e]], 1);
    }
    return;
  }

  __shared__ unsigned short xb[64][72];  // bf16 x tile, padded
  __shared__ unsigned short wb[64][72];  // bf16 W slice, padded
  __shared__ float cb[64][68];           // fp32 bounce for k/v repack
  const int tileN = blockIdx.x * 64;

  {  // stage x -> bf16 LDS
    const int nl = t >> 2, c0 = (t & 3) * 16;
    const int n = tileN + nl;
    float4 a0, a1, a2, a3;
    if (n < NN) {
      const float4* xr = (const float4*)(x + (size_t)n * 64 + c0);
      a0 = xr[0]; a1 = xr[1]; a2 = xr[2]; a3 = xr[3];
    } else {
      a0 = a1 = a2 = a3 = make_float4(0.f, 0.f, 0.f, 0.f);
    }
    *(uint4*)&xb[nl][c0] =
        make_uint4(pk2(a0.x, a0.y), pk2(a0.z, a0.w), pk2(a1.x, a1.y), pk2(a1.z, a1.w));
    *(uint4*)&xb[nl][c0 + 8] =
        make_uint4(pk2(a2.x, a2.y), pk2(a2.z, a2.w), pk2(a3.x, a3.y), pk2(a3.z, a3.w));
  }

  const int w = t >> 6;          // wave -> 16-node row tile
  const int l = t & 63;
  const int rb = w * 16;
  const int frow = l & 15;
  const int fk = (l >> 4) * 8;

  const bf16x8 a0 = *(const bf16x8*)&xb[rb + frow][fk];
  const bf16x8 a1 = *(const bf16x8*)&xb[rb + frow][fk + 32];

  for (int s = 0; s < 7; s++) {
    const float* Wb; const float* bias; int cbase; int kind;  // 0 q,1 skip,2 k,3 v
    switch (s) {
      case 0: Wb = Wq;    bias = bq;    cbase = 0;  kind = 0; break;
      case 1: Wb = Wq;    bias = bq;    cbase = 64; kind = 0; break;
      case 2: Wb = Wk;    bias = bk;    cbase = 0;  kind = 2; break;
      case 3: Wb = Wv;    bias = bv;    cbase = 0;  kind = 3; break;
      case 4: Wb = Wk;    bias = bk;    cbase = 64; kind = 2; break;
      case 5: Wb = Wv;    bias = bv;    cbase = 64; kind = 3; break;
      default: Wb = Wskip; bias = bskip; cbase = 0; kind = 1; break;
    }

    __syncthreads();
    {
      const int nl = t >> 2, c0 = (t & 3) * 16;
      const float4* wr = (const float4*)(Wb + (size_t)(cbase + nl) * 64 + c0);
      float4 b0 = wr[0], b1 = wr[1], b2 = wr[2], b3 = wr[3];
      *(uint4*)&wb[nl][c0] =
          make_uint4(pk2(b0.x, b0.y), pk2(b0.z, b0.w), pk2(b1.x, b1.y), pk2(b1.z, b1.w));
      *(uint4*)&wb[nl][c0 + 8] =
          make_uint4(pk2(b2.x, b2.y), pk2(b2.z, b2.w), pk2(b3.x, b3.y), pk2(b3.z, b3.w));
    }
    __syncthreads();

    #pragma unroll
    for (int ct = 0; ct < 4; ct++) {
      const bf16x8 b0 = *(const bf16x8*)&wb[ct * 16 + frow][fk];
      const bf16x8 b1 = *(const bf16x8*)&wb[ct * 16 + frow][fk + 32];
      f32x4 acc = {0.f, 0.f, 0.f, 0.f};
      acc = __builtin_amdgcn_mfma_f32_16x16x32_bf16(a0, b0, acc, 0, 0, 0);
      acc = __builtin_amdgcn_mfma_f32_16x16x32_bf16(a1, b1, acc, 0, 0, 0);
      const int col = ct * 16 + frow;          // D: col = lane&15
      const int row0 = rb + ((l >> 4) << 2);   // D: row = (lane>>4)*4 + j
      const float bb = bias[cbase * (kind != 1 ? 1 : 0) + col];
      if (kind == 0) {
        #pragma unroll
        for (int j = 0; j < 4; j++) {
          const int n = tileN + row0 + j;
          if (n < NN) qs[(size_t)n * 128 + cbase + col] = acc[j] + bb;
        }
      } else if (kind == 1) {
        #pragma unroll
        for (int j = 0; j < 4; j++) {
          const int n = tileN + row0 + j;
          if (n < NN) skip[(size_t)n * 64 + col] = acc[j] + bb;
        }
      } else {
        #pragma unroll
        for (int j = 0; j < 4; j++) cb[row0 + j][col] = acc[j] + bb;
      }
    }

    if (kind >= 2) {  // fp8 repack from this wave's own cb rows (intra-wave)
      const int rrow = rb + (l >> 2);
      const int chb = (l & 3) * 16;
      const int n = tileN + rrow;
      if (n < NN) {
        const float4* c4 = (const float4*)&cb[rrow][chb];
        const float4 c0_ = c4[0], c1_ = c4[1], c2_ = c4[2], c3_ = c4[3];
        unsigned p0 = 0, p1 = 0, p2 = 0, p3 = 0;
        p0 = __builtin_amdgcn_cvt_pk_fp8_f32(c0_.x, c0_.y, p0, false);
        p0 = __builtin_amdgcn_cvt_pk_fp8_f32(c0_.z, c0_.w, p0, true);
        p1 = __builtin_amdgcn_cvt_pk_fp8_f32(c1_.x, c1_.y, p1, false);
        p1 = __builtin_amdgcn_cvt_pk_fp8_f32(c1_.z, c1_.w, p1, true);
        p2 = __builtin_amdgcn_cvt_pk_fp8_f32(c2_.x, c2_.y, p2, false);
        p2 = __builtin_amdgcn_cvt_pk_fp8_f32(c2_.z, c2_.w, p2, true);
        p3 = __builtin_amdgcn_cvt_pk_fp8_f32(c3_.x, c3_.y, p3, false);
        p3 = __builtin_amdgcn_cvt_pk_fp8_f32(c3_.z, c3_.w, p3, true);
        const int ebase = (cbase + chb) >> 2;
        unsigned* dstp = kvp + (size_t)n * 64 + ebase * 2 + ((kind == 3) ? 1 : 0);
        dstp[0] = p0; dstp[2] = p1; dstp[4] = p2; dstp[6] = p3;
      }
    }
  }
}

// ---------------- S2: single merged scan (49 blocks; self-computed prefix) --
__global__ __launch_bounds__(1024) void k_scan(
    const int* __restrict__ cnt, int* __restrict__ rowptr) {
  __shared__ int wsum[16];
  __shared__ int boff_s;
  const int t = threadIdx.x, lane = t & 63, wid = t >> 6;
  const int b = blockIdx.x;

  {  // prefix: sum of cnt[0 .. b*1024)
    int pre = 0;
    for (int j = t; j < b * 1024; j += 1024) pre += cnt[j];
    #pragma unroll
    for (int m = 1; m <= 32; m <<= 1) pre += __shfl_xor(pre, m);
    if (lane == 0) wsum[wid] = pre;
    __syncthreads();
    if (t == 0) {
      int s = 0;
      #pragma unroll
      for (int j = 0; j < 16; j++) s += wsum[j];
      boff_s = s;
    }
    __syncthreads();
  }

  const int i = b * 1024 + t;
  const int val = (i < NN) ? cnt[i] : 0;
  int incl = val;
  #pragma unroll
  for (int off = 1; off < 64; off <<= 1) {
    int n = __shfl_up(incl, off, 64);
    if (lane >= off) incl += n;
  }
  if (lane == 63) wsum[wid] = incl;
  __syncthreads();
  if (t < 16) {
    int wv = wsum[t];
    int wincl = wv;
    #pragma unroll
    for (int off = 1; off < 16; off <<= 1) {
      int n = __shfl_up(wincl, off, 64);
      if (t >= off) wincl += n;
    }
    wsum[t] = wincl - wv;
  }
  __syncthreads();
  if (i < NN) rowptr[i] = boff_s + wsum[wid] + incl - val;
  if (b == 0 && t == 0) rowptr[NN] = NE;
}

// ---------------- S3: pure scatter fill (no atomics), 4B records ------------
__global__ __launch_bounds__(256) void k_fill(
    const int* __restrict__ ei, const float* __restrict__ ea,
    const int* __restrict__ rowptr, const int* __restrict__ pos,
    unsigned* __restrict__ epk) {
  const int e = blockIdx.x * 256 + threadIdx.x;
  if (e < NE) {
    const int dst = ei[NE + e];
    const int idx = rowptr[dst] + pos[e];
    const unsigned rec = (unsigned)ei[e] |
        ((unsigned)__half_as_ushort(__float2half_rn(ea[e])) << 16);
    epk[idx] = rec;
  }
}

// ------- K2: per-dst softmax + agg (fp8 kv, DPP reduce, 8-edge unroll),
//         single barrier after wlT staging; waves independent afterwards -----
__global__ __launch_bounds__(256) void k_fused(
    const float* __restrict__ qs, const unsigned* __restrict__ kvp,
    const float* __restrict__ skip, const float* __restrict__ x,
    const int* __restrict__ rowptr, const unsigned* __restrict__ epk,
    const float* __restrict__ We,
    const float* __restrict__ Wl, const float* __restrict__ bl,
    const float* __restrict__ g0, const float* __restrict__ b0,
    const float* __restrict__ g1, const float* __restrict__ b1,
    float* __restrict__ out)
{
  __shared__ float wlT[64][65];   // wlT[k][j] = Wl[j][k]
  __shared__ float scx[4][64];    // per-wave scratch (transpose + x1 broadcast)
  const int t = threadIdx.x;
  {
    const int jl = t >> 2, c0 = (t & 3) * 16;
    const float4* wr = (const float4*)(Wl + (size_t)jl * 64 + c0);
    float4 w0 = wr[0], w1 = wr[1], w2 = wr[2], w3 = wr[3];
    wlT[c0 +  0][jl] = w0.x; wlT[c0 +  1][jl] = w0.y; wlT[c0 +  2][jl] = w0.z; wlT[c0 +  3][jl] = w0.w;
    wlT[c0 +  4][jl] = w1.x; wlT[c0 +  5][jl] = w1.y; wlT[c0 +  6][jl] = w1.z; wlT[c0 +  7][jl] = w1.w;
    wlT[c0 +  8][jl] = w2.x; wlT[c0 +  9][jl] = w2.y; wlT[c0 + 10][jl] = w2.z; wlT[c0 + 11][jl] = w2.w;
    wlT[c0 + 12][jl] = w3.x; wlT[c0 + 13][jl] = w3.y; wlT[c0 + 14][jl] = w3.z; wlT[c0 + 15][jl] = w3.w;
  }
  __syncthreads();  // the ONLY barrier

  const int w = t >> 6;
  const int dst = __builtin_amdgcn_readfirstlane(blockIdx.x * 4 + w);
  const int lane = t & 63;
  const int half = lane >> 5;
  const int el = lane & 31;

  const float4 qv = ((const float4*)(qs + (size_t)dst * 128))[el];
  const float4 we4 = ((const float4*)We)[el];
  const float skipv = skip[(size_t)dst * 64 + lane];
  const float xv    = x[(size_t)dst * 64 + lane];

  const float qwe = red16(qv.x * we4.x + qv.y * we4.y + qv.z * we4.z + qv.w * we4.w);

  const int base = rowptr[dst];
  const int deg  = rowptr[dst + 1] - base;
  const uint2* kv8 = (const uint2*)kvp;
  const unsigned* ep = epk + base;

  float s = 0.f, sw = 0.f;
  float sv0 = 0.f, sv1 = 0.f, sv2 = 0.f, sv3 = 0.f;

  const float SCL = 0.18033688011112042f;  // 0.125*log2(e)

#define UNPACK_W(er) __half2float(__ushort_as_half((unsigned short)((er) >> 16)))
#define PROC(u, wg, mask)                                                   \
  {                                                                         \
    const v2f k01 = __builtin_amdgcn_cvt_pk_f32_fp8((u).x, false);          \
    const v2f k23 = __builtin_amdgcn_cvt_pk_f32_fp8((u).x, true);           \
    const v2f v01 = __builtin_amdgcn_cvt_pk_f32_fp8((u).y, false);          \
    const v2f v23 = __builtin_amdgcn_cvt_pk_f32_fp8((u).y, true);           \
    const float p = red16(qv.x * k01.x + qv.y * k01.y +                     \
                          qv.z * k23.x + qv.w * k23.y);                     \
    float e_ = exp2f((p + (wg) * qwe) * SCL);                               \
    e_ = (mask) ? e_ : 0.f;                                                 \
    s += e_; sw += e_ * (wg);                                               \
    sv0 += e_ * v01.x; sv1 += e_ * v01.y;                                   \
    sv2 += e_ * v23.x; sv3 += e_ * v23.y;                                   \
  }

  int i = 0;
  for (; i + 8 <= deg; i += 8) {
    const unsigned er0 = ep[i + half];
    const unsigned er1 = ep[i + 2 + half];
    const unsigned er2 = ep[i + 4 + half];
    const unsigned er3 = ep[i + 6 + half];
    const uint2 u0 = kv8[(size_t)(er0 & 0xFFFFu) * 32 + el];
    const uint2 u1 = kv8[(size_t)(er1 & 0xFFFFu) * 32 + el];
    const uint2 u2 = kv8[(size_t)(er2 & 0xFFFFu) * 32 + el];
    const uint2 u3 = kv8[(size_t)(er3 & 0xFFFFu) * 32 + el];
    PROC(u0, UNPACK_W(er0), true)
    PROC(u1, UNPACK_W(er1), true)
    PROC(u2, UNPACK_W(er2), true)
    PROC(u3, UNPACK_W(er3), true)
  }
  for (; i + 4 <= deg; i += 4) {
    const unsigned er0 = ep[i + half];
    const unsigned er1 = ep[i + 2 + half];
    const uint2 u0 = kv8[(size_t)(er0 & 0xFFFFu) * 32 + el];
    const uint2 u1 = kv8[(size_t)(er1 & 0xFFFFu) * 32 + el];
    PROC(u0, UNPACK_W(er0), true)
    PROC(u1, UNPACK_W(er1), true)
  }
  for (; i < deg; i += 2) {
    const int idx = i + half;
    const bool valid = idx < deg;
    const unsigned er = ep[valid ? idx : (deg - 1)];
    const uint2 u = kv8[(size_t)(er & 0xFFFFu) * 32 + el];
    PROC(u, UNPACK_W(er), valid)
  }
#undef PROC
#undef UNPACK_W

  s  += __shfl_xor(s, 32);
  sw += __shfl_xor(sw, 32);
  sv0 += __shfl_xor(sv0, 32); sv1 += __shfl_xor(sv1, 32);
  sv2 += __shfl_xor(sv2, 32); sv3 += __shfl_xor(sv3, 32);

  float a0 = 0.f, a1 = 0.f, a2 = 0.f, a3 = 0.f;
  if (deg > 0) {
    const float inv = 1.f / s;
    a0 = (sv0 + sw * we4.x) * inv;
    a1 = (sv1 + sw * we4.y) * inv;
    a2 = (sv2 + sw * we4.z) * inv;
    a3 = (sv3 + sw * we4.w) * inv;
  }
  a0 = 0.5f * (a0 + __shfl_xor(a0, 16));
  a1 = 0.5f * (a1 + __shfl_xor(a1, 16));
  a2 = 0.5f * (a2 + __shfl_xor(a2, 16));
  a3 = 0.5f * (a3 + __shfl_xor(a3, 16));
  if (half == 0 && el < 16) {
    ((float4*)scx[w])[el] = make_float4(a0, a1, a2, a3);
  }
  const float hv = scx[w][lane] + skipv;

  // LN0 via dual moments
  float m1 = hv, m2 = hv * hv;
  m1 = red16(m1); m2 = red16(m2);
  m1 += __shfl_xor(m1, 16); m2 += __shfl_xor(m2, 16);
  m1 += __shfl_xor(m1, 32); m2 += __shfl_xor(m2, 32);
  const float mean = m1 * (1.f / 64.f);
  const float var = fmaxf(m2 * (1.f / 64.f) - mean * mean, 0.f);
  const float x1 = xv + (hv - mean) * rsqrtf(var + 1e-5f) * g0[lane] + b0[lane];

  // y = x1 @ Wl^T + bl via per-wave LDS broadcast
  scx[w][lane] = x1;
  float y0 = 0.f, y1 = 0.f, y2 = 0.f, y3 = 0.f;
  #pragma unroll
  for (int kk = 0; kk < 64; kk += 4) {
    const float4 xb4 = *(const float4*)&scx[w][kk];
    y0 += xb4.x * wlT[kk][lane];
    y1 += xb4.y * wlT[kk + 1][lane];
    y2 += xb4.z * wlT[kk + 2][lane];
    y3 += xb4.w * wlT[kk + 3][lane];
  }
  const float y = bl[lane] + (y0 + y1) + (y2 + y3);

  // LN1 via dual moments
  float n1 = y, n2 = y * y;
  n1 = red16(n1); n2 = red16(n2);
  n1 += __shfl_xor(n1, 16); n2 += __shfl_xor(n2, 16);
  n1 += __shfl_xor(n1, 32); n2 += __shfl_xor(n2, 32);
  const float mean2 = n1 * (1.f / 64.f);
  const float var2 = fmaxf(n2 * (1.f / 64.f) - mean2 * mean2, 0.f);
  out[(size_t)dst * 64 + lane] = x1 + (y - mean2) * rsqrtf(var2 + 1e-5f) * g1[lane] + b1[lane];
}

extern "C" void kernel_launch(void* const* d_in, const int* in_sizes, int n_in,
                              void* d_out, int out_size, void* d_ws, size_t ws_size,
                              hipStream_t stream) {
  const float* x     = (const float*)d_in[0];
  const int*   ei    = (const int*)d_in[1];
  const float* ea    = (const float*)d_in[2];
  const float* Wq    = (const float*)d_in[3];
  const float* bq    = (const float*)d_in[4];
  const float* Wk    = (const float*)d_in[5];
  const float* bk    = (const float*)d_in[6];
  const float* Wv    = (const float*)d_in[7];
  const float* bv    = (const float*)d_in[8];
  const float* We    = (const float*)d_in[9];
  const float* Wskip = (const float*)d_in[10];
  const float* bskip = (const float*)d_in[11];
  const float* Wl    = (const float*)d_in[12];
  const float* bl    = (const float*)d_in[13];
  const float* g0    = (const float*)d_in[14];
  const float* b0    = (const float*)d_in[15];
  const float* g1    = (const float*)d_in[16];
  const float* b1    = (const float*)d_in[17];
  float* out = (float*)d_out;

  float* ws = (float*)d_ws;
  size_t off = 0;
  float* qs   = ws + off; off += (size_t)NN * 128;
  unsigned* kvp = (unsigned*)(ws + off); off += (size_t)NN * 64;  // 256B/node fp8
  float* skip = ws + off; off += (size_t)NN * 64;
  int* cnt    = (int*)(ws + off); off += NN;
  int* rowptr = (int*)(ws + off); off += NN + 1;
  int* pos    = (int*)(ws + off); off += NE;
  unsigned* epk = (unsigned*)(ws + off); off += NE;

  (void)hipMemsetAsync(cnt, 0, (size_t)NN * sizeof(int), stream);

  dim3 gGemm((NN + 63) / 64, 2);  // y==1 -> histogram+pos slice
  hipLaunchKernelGGL(k_gemm_qkv, gGemm, dim3(256), 0, stream,
                     x, Wq, bq, Wk, bk, Wv, bv, Wskip, bskip, ei, cnt, pos, qs, kvp, skip);
  hipLaunchKernelGGL(k_scan, dim3(49), dim3(1024), 0, stream, cnt, rowptr);
  hipLaunchKernelGGL(k_fill, dim3((NE + 255) / 256), dim3(256), 0, stream,
                     ei, ea, rowptr, pos, epk);
  hipLaunchKernelGGL(k_fused, dim3(NN / 4), dim3(256), 0, stream,
                     qs, kvp, skip, x, rowptr, epk, We,
                     Wl, bl, g0, b0, g1, b1, out);
}